// Round 1
// baseline (1409.906 us; speedup 1.0000x reference)
//
#include <hip/hip_runtime.h>

// EncoderGRUODE: B=256, T=512, D_IN=64, H=128
// One workgroup (512 thr) per batch sample, persistent over all 512 time steps.
// All weights register-resident (float4 slices, interleaved quad k-split).
// LDS holds only the 128-d hidden vectors + 64-d input/prev_out buffers.

#define NB    256   // batch / blocks
#define TB    512   // threads per block
#define TSTEP 512   // time steps
#define DIN   64
#define HD    128

__device__ __forceinline__ float fast_tanh(float v) {
    float e = __expf(2.0f * v);
    return 1.0f - 2.0f / (e + 1.0f);
}
__device__ __forceinline__ float fast_sigmoid(float v) {
    return 1.0f / (1.0f + __expf(-v));
}

__global__ __launch_bounds__(TB, 2) void gruode_kernel(
    const float* __restrict__ x,         // [B, T, DIN]
    const float* __restrict__ tp,        // [B, T] (row 0 used)
    const int*   __restrict__ samp_mask, // [T] bool -> int32
    const float* __restrict__ W_ih,      // [3H, DIN]
    const float* __restrict__ W_hh,      // [3H, H]
    const float* __restrict__ b_ih,      // [3H]
    const float* __restrict__ b_hh,      // [3H]
    const float* __restrict__ W_node,    // [H, H]
    const float* __restrict__ b_node,    // [H]
    const float* __restrict__ W_out,     // [DIN, H]
    const float* __restrict__ b_out,     // [DIN]
    float*       __restrict__ out)       // [B*T, DIN]
{
    const int t   = threadIdx.x;   // 0..511
    const int b   = blockIdx.x;    // sample
    const int j   = t >> 2;        // 0..127 : hidden row owned by this quad
    const int kq  = t & 3;         // quad slice of k-dim
    const int j64 = t >> 3;        // 0..63  : output row owned by this octet
    const int ko  = t & 7;         // octet slice of k-dim

    __shared__ __align__(16) float sh_h [HD];
    __shared__ __align__(16) float sh_t0[HD];
    __shared__ __align__(16) float sh_t1[HD];
    __shared__ __align__(16) float sh_in[DIN];
    __shared__ __align__(16) float sh_po[DIN];

    const float4* Wn4  = (const float4*)W_node;  // [128][32 f4]
    const float4* Whh4 = (const float4*)W_hh;    // [384][32 f4]
    const float4* Wih4 = (const float4*)W_ih;    // [384][16 f4]
    const float4* Wo4  = (const float4*)W_out;   // [64][32 f4]

    // ---- weights -> registers (one-time; interleaved f4 slices match LDS reads)
    float4 Wn[8], Whr[8], Whz[8], Whn[8];
    #pragma unroll
    for (int i = 0; i < 8; ++i) {
        Wn [i] = Wn4 [j*32 + i*4 + kq];
        Whr[i] = Whh4[(0*HD + j)*32 + i*4 + kq];
        Whz[i] = Whh4[(1*HD + j)*32 + i*4 + kq];
        Whn[i] = Whh4[(2*HD + j)*32 + i*4 + kq];
    }
    float4 Wir[4], Wiz[4], Win[4], Wo[4];
    #pragma unroll
    for (int i = 0; i < 4; ++i) {
        Wir[i] = Wih4[(0*HD + j)*16 + i*4 + kq];
        Wiz[i] = Wih4[(1*HD + j)*16 + i*4 + kq];
        Win[i] = Wih4[(2*HD + j)*16 + i*4 + kq];
        Wo [i] = Wo4 [j64*32 + i*8 + ko];
    }

    const float bn   = b_node[j];
    const float br   = b_ih[0*HD + j] + b_hh[0*HD + j];
    const float bz   = b_ih[1*HD + j] + b_hh[1*HD + j];
    const float bi_n = b_ih[2*HD + j];
    const float bh_n = b_hh[2*HD + j];
    const float bo   = b_out[j64];

    if (t < HD)  sh_h[t]  = 0.0f;     // h0 = 0
    if (t < DIN) sh_po[t] = b_out[t]; // prev_out(h0) = b_out
    __syncthreads();

    const float4* h4  = (const float4*)sh_h;
    const float4* t04 = (const float4*)sh_t0;
    const float4* t14 = (const float4*)sh_t1;
    const float4* in4 = (const float4*)sh_in;

    // quad-sliced dot over a 128-float LDS buffer (32 MACs/thread)
    auto hdot = [&](const float4 (&w)[8], const float4* buf) -> float {
        float ax = 0.f, ay = 0.f, az = 0.f, aw = 0.f;
        #pragma unroll
        for (int i = 0; i < 8; ++i) {
            float4 v = buf[i*4 + kq];
            ax = fmaf(w[i].x, v.x, ax);
            ay = fmaf(w[i].y, v.y, ay);
            az = fmaf(w[i].z, v.z, az);
            aw = fmaf(w[i].w, v.w, aw);
        }
        return (ax + ay) + (az + aw);
    };
    // quad-sliced dot over a 64-float LDS buffer (16 MACs/thread)
    auto idot = [&](const float4 (&w)[4], const float4* buf) -> float {
        float ax = 0.f, ay = 0.f, az = 0.f, aw = 0.f;
        #pragma unroll
        for (int i = 0; i < 4; ++i) {
            float4 v = buf[i*4 + kq];
            ax = fmaf(w[i].x, v.x, ax);
            ay = fmaf(w[i].y, v.y, ay);
            az = fmaf(w[i].z, v.z, az);
            aw = fmaf(w[i].w, v.w, aw);
        }
        return (ax + ay) + (az + aw);
    };
    auto qred = [](float v) -> float {  // reduce over quad (lanes t^1, t^2)
        v += __shfl_xor(v, 1);
        v += __shfl_xor(v, 2);
        return v;
    };

    float tp_prev = 0.0f;

    #pragma unroll 1
    for (int s = 0; s < TSTEP; ++s) {
        // dt (uniform scalar)
        float tpv = tp[s];
        float dt  = (s == 0) ? 0.01f : (tpv - tp_prev);
        tp_prev = tpv;

        // teacher-forcing input select (uniform branch)
        bool use_x = (samp_mask[s] != 0);
        if (t < DIN) {
            sh_in[t] = use_x ? x[((size_t)b * TSTEP + s) * DIN + t] : sh_po[t];
        }

        float hj = sh_h[j];

        // ---- RK4: dh/dt = tanh(h @ Wn^T + bn) ----
        float p  = qred(hdot(Wn, h4));
        float k1 = fast_tanh(p + bn);
        if (kq == 0) sh_t0[j] = fmaf(0.5f * dt, k1, hj);
        __syncthreads();                                   // B1

        p = qred(hdot(Wn, t04));
        float k2 = fast_tanh(p + bn);
        if (kq == 0) sh_t1[j] = fmaf(0.5f * dt, k2, hj);
        __syncthreads();                                   // B2

        p = qred(hdot(Wn, t14));
        float k3 = fast_tanh(p + bn);
        if (kq == 0) sh_t0[j] = fmaf(dt, k3, hj);
        __syncthreads();                                   // B3

        p = qred(hdot(Wn, t04));
        float k4 = fast_tanh(p + bn);
        float hode = fmaf(dt * (1.0f / 6.0f),
                          (k1 + 2.0f * k2) + (2.0f * k3 + k4), hj);
        if (kq == 0) sh_t1[j] = hode;                      // sh_t1 = h_ode
        __syncthreads();                                   // B4

        // ---- GRU cell: inp from sh_in, hidden from h_ode ----
        float ghr = hdot(Whr, t14);
        float ghz = hdot(Whz, t14);
        float ghn = hdot(Whn, t14);
        float gir = idot(Wir, in4);
        float giz = idot(Wiz, in4);
        float gin = idot(Win, in4);

        float rr  = fast_sigmoid(qred(ghr + gir) + br);
        float zz  = fast_sigmoid(qred(ghz + giz) + bz);
        float hnv = qred(ghn) + bh_n;
        float inv = qred(gin) + bi_n;
        float nn  = fast_tanh(fmaf(rr, hnv, inv));
        float hnew = fmaf(zz, hode - nn, nn);   // (1-z)*n + z*h_ode

        if (kq == 0) sh_h[j] = hnew;
        __syncthreads();                                   // B5

        // ---- out_t = h_new @ W_out^T + b_out  (also next step's prev_out) ----
        float ax = 0.f, ay = 0.f, az = 0.f, aw = 0.f;
        #pragma unroll
        for (int i = 0; i < 4; ++i) {
            float4 v = h4[i*8 + ko];
            ax = fmaf(Wo[i].x, v.x, ax);
            ay = fmaf(Wo[i].y, v.y, ay);
            az = fmaf(Wo[i].z, v.z, az);
            aw = fmaf(Wo[i].w, v.w, aw);
        }
        float o = (ax + ay) + (az + aw);
        o += __shfl_xor(o, 1);
        o += __shfl_xor(o, 2);
        o += __shfl_xor(o, 4);
        o += bo;
        if (ko == 0) {
            sh_po[j64] = o;
            out[((size_t)b * TSTEP + s) * DIN + j64] = o;
        }
        __syncthreads();                                   // B6
    }
}

extern "C" void kernel_launch(void* const* d_in, const int* in_sizes, int n_in,
                              void* d_out, int out_size, void* d_ws, size_t ws_size,
                              hipStream_t stream) {
    (void)in_sizes; (void)n_in; (void)d_ws; (void)ws_size; (void)out_size;
    const float* x      = (const float*)d_in[0];
    const float* tp     = (const float*)d_in[1];
    const int*   mask   = (const int*)  d_in[2];
    const float* W_ih   = (const float*)d_in[3];
    const float* W_hh   = (const float*)d_in[4];
    const float* b_ih   = (const float*)d_in[5];
    const float* b_hh   = (const float*)d_in[6];
    const float* W_node = (const float*)d_in[7];
    const float* b_node = (const float*)d_in[8];
    const float* W_out  = (const float*)d_in[9];
    const float* b_out  = (const float*)d_in[10];
    float* outp = (float*)d_out;

    gruode_kernel<<<NB, TB, 0, stream>>>(x, tp, mask, W_ih, W_hh, b_ih, b_hh,
                                         W_node, b_node, W_out, b_out, outp);
}

// Round 2
// 1224.791 us; speedup vs baseline: 1.1511x; 1.1511x over previous
//
#include <hip/hip_runtime.h>

// EncoderGRUODE: B=256, T=512, D_IN=64, H=128
// One workgroup (512 thr) per sample, persistent over all 512 steps.
// R2: weights pinned in VGPRs via asm opacity (R1 showed VGPR=128 -> compiler
// re-fetched 384KB/block/step from L2 = measured 1465us at L2 BW).
// Packed v_pk_fma_f32 dots, DPP quad reductions (VALU pipe, not LDS),
// x/tp/mask software-pipelined one step ahead.

#define NB    256
#define TB    512
#define TSTEP 512
#define DIN   64
#define HD    128

typedef float v2f __attribute__((ext_vector_type(2)));

__device__ __forceinline__ float fast_tanh(float v) {
    float e = __expf(2.0f * v);
    return 1.0f - 2.0f / (e + 1.0f);
}
__device__ __forceinline__ float fast_sigmoid(float v) {
    return 1.0f / (1.0f + __expf(-v));
}

// quad butterfly reduction via DPP quad_perm (VALU pipe; zero LDS traffic)
__device__ __forceinline__ float quad_red(float v) {
    v += __int_as_float(__builtin_amdgcn_update_dpp(
            0, __float_as_int(v), 0xB1, 0xF, 0xF, true)); // xor 1: [1,0,3,2]
    v += __int_as_float(__builtin_amdgcn_update_dpp(
            0, __float_as_int(v), 0x4E, 0xF, 0xF, true)); // xor 2: [2,3,0,1]
    return v;
}

__global__ __launch_bounds__(TB, 2) void gruode_kernel(
    const float* __restrict__ x,         // [B, T, DIN]
    const float* __restrict__ tp,        // [B, T] (row 0 used)
    const int*   __restrict__ samp_mask, // [T]
    const float* __restrict__ W_ih,      // [3H, DIN]
    const float* __restrict__ W_hh,      // [3H, H]
    const float* __restrict__ b_ih,      // [3H]
    const float* __restrict__ b_hh,      // [3H]
    const float* __restrict__ W_node,    // [H, H]
    const float* __restrict__ b_node,    // [H]
    const float* __restrict__ W_out,     // [DIN, H]
    const float* __restrict__ b_out,     // [DIN]
    float*       __restrict__ out)       // [B*T, DIN]
{
    const int t   = threadIdx.x;
    const int b   = blockIdx.x;
    const int j   = t >> 2;        // hidden row owned by this quad
    const int kq  = t & 3;         // quad k-slice
    const int j64 = t >> 3;        // output row owned by this octet
    const int ko  = t & 7;         // octet k-slice

    __shared__ __align__(16) float sh_h [HD];
    __shared__ __align__(16) float sh_t0[HD];
    __shared__ __align__(16) float sh_t1[HD];
    __shared__ __align__(16) float sh_in[DIN];
    __shared__ __align__(16) float sh_po[DIN];

    const float4* Wn4  = (const float4*)W_node;  // [128][32 f4]
    const float4* Whh4 = (const float4*)W_hh;    // [384][32 f4]
    const float4* Wih4 = (const float4*)W_ih;    // [384][16 f4]
    const float4* Wo4  = (const float4*)W_out;   // [64][32 f4]

    // ---- weights -> registers as float2 pairs (192 VGPRs total) ----
    v2f Wn[16], Whr[16], Whz[16], Whn[16];
    #pragma unroll
    for (int i = 0; i < 8; ++i) {
        float4 w;
        w = Wn4 [j*32 + i*4 + kq];          Wn [2*i] = (v2f){w.x, w.y}; Wn [2*i+1] = (v2f){w.z, w.w};
        w = Whh4[(0*HD + j)*32 + i*4 + kq]; Whr[2*i] = (v2f){w.x, w.y}; Whr[2*i+1] = (v2f){w.z, w.w};
        w = Whh4[(1*HD + j)*32 + i*4 + kq]; Whz[2*i] = (v2f){w.x, w.y}; Whz[2*i+1] = (v2f){w.z, w.w};
        w = Whh4[(2*HD + j)*32 + i*4 + kq]; Whn[2*i] = (v2f){w.x, w.y}; Whn[2*i+1] = (v2f){w.z, w.w};
    }
    v2f Wir[8], Wiz[8], Win[8], Wo[8];
    #pragma unroll
    for (int i = 0; i < 4; ++i) {
        float4 w;
        w = Wih4[(0*HD + j)*16 + i*4 + kq]; Wir[2*i] = (v2f){w.x, w.y}; Wir[2*i+1] = (v2f){w.z, w.w};
        w = Wih4[(1*HD + j)*16 + i*4 + kq]; Wiz[2*i] = (v2f){w.x, w.y}; Wiz[2*i+1] = (v2f){w.z, w.w};
        w = Wih4[(2*HD + j)*16 + i*4 + kq]; Win[2*i] = (v2f){w.x, w.y}; Win[2*i+1] = (v2f){w.z, w.w};
        w = Wo4 [j64*32 + i*8 + ko];        Wo [2*i] = (v2f){w.x, w.y}; Wo [2*i+1] = (v2f){w.z, w.w};
    }
    // Pin: opaque to rematerialization — forces true residency.
    #pragma unroll
    for (int i = 0; i < 16; ++i) {
        asm volatile("" : "+v"(Wn[i]));  asm volatile("" : "+v"(Whr[i]));
        asm volatile("" : "+v"(Whz[i])); asm volatile("" : "+v"(Whn[i]));
    }
    #pragma unroll
    for (int i = 0; i < 8; ++i) {
        asm volatile("" : "+v"(Wir[i])); asm volatile("" : "+v"(Wiz[i]));
        asm volatile("" : "+v"(Win[i])); asm volatile("" : "+v"(Wo[i]));
    }

    const float bn   = b_node[j];
    const float br   = b_ih[0*HD + j] + b_hh[0*HD + j];
    const float bz   = b_ih[1*HD + j] + b_hh[1*HD + j];
    const float bi_n = b_ih[2*HD + j];
    const float bh_n = b_hh[2*HD + j];
    const float bo   = b_out[j64];

    if (t < HD)  sh_h[t]  = 0.0f;
    if (t < DIN) sh_po[t] = b_out[t];

    // software-pipelined uniform/stream state
    float tp_cur  = tp[0];
    float tp_prev = tp_cur - 0.01f;          // dts[0] = 0.01
    int   m_cur   = samp_mask[0];
    float xr = (t < DIN) ? x[(size_t)b * TSTEP * DIN + t] : 0.0f;

    __syncthreads();

    const float4* h4  = (const float4*)sh_h;
    const float4* t04 = (const float4*)sh_t0;
    const float4* t14 = (const float4*)sh_t1;
    const float4* in4 = (const float4*)sh_in;

    // packed quad-sliced dot over a 128-float LDS vector
    auto hdot = [&](const v2f (&w)[16], const float4* buf) -> float {
        v2f a0 = {0.f, 0.f}, a1 = {0.f, 0.f};
        #pragma unroll
        for (int i = 0; i < 8; ++i) {
            float4 v = buf[i*4 + kq];
            a0 += w[2*i]   * (v2f){v.x, v.y};
            a1 += w[2*i+1] * (v2f){v.z, v.w};
        }
        v2f a = a0 + a1;
        return a.x + a.y;
    };

    float hj = 0.0f;   // h carried in registers (all quad lanes hold row j)

    #pragma unroll 1
    for (int s = 0; s < TSTEP; ++s) {
        const float dt = tp_cur - tp_prev;

        // teacher-forcing input (uniform branch; wave 0 only writes)
        if (t < DIN) sh_in[t] = m_cur ? xr : sh_po[t];

        // prefetch next step's stream data (latency hidden behind RK4)
        {
            const int sn = (s + 1 < TSTEP) ? s + 1 : s;
            tp_prev = tp_cur;
            tp_cur  = tp[sn];
            m_cur   = samp_mask[sn];
            if (t < DIN) xr = x[((size_t)b * TSTEP + sn) * DIN + t];
        }

        // ---- RK4 on dh/dt = tanh(Wn h + bn) ----
        float k1 = fast_tanh(quad_red(hdot(Wn, h4)) + bn);
        if (kq == 0) sh_t0[j] = fmaf(0.5f * dt, k1, hj);
        __syncthreads();                                   // B1

        float k2 = fast_tanh(quad_red(hdot(Wn, t04)) + bn);
        if (kq == 0) sh_t1[j] = fmaf(0.5f * dt, k2, hj);
        __syncthreads();                                   // B2

        float k3 = fast_tanh(quad_red(hdot(Wn, t14)) + bn);
        if (kq == 0) sh_t0[j] = fmaf(dt, k3, hj);
        __syncthreads();                                   // B3

        float k4 = fast_tanh(quad_red(hdot(Wn, t04)) + bn);
        float hode = fmaf(dt * (1.0f / 6.0f),
                          (k1 + 2.0f * k2) + (2.0f * k3 + k4), hj);
        if (kq == 0) sh_t1[j] = hode;                      // t1 = h_ode vector
        __syncthreads();                                   // B4

        // ---- GRU cell (one pass over t1 and in; 3 gates share loads) ----
        v2f ar = {0.f,0.f}, az = {0.f,0.f}, an = {0.f,0.f};
        #pragma unroll
        for (int i = 0; i < 8; ++i) {
            float4 v = t14[i*4 + kq];
            v2f lo = {v.x, v.y}, hi = {v.z, v.w};
            ar += Whr[2*i] * lo; ar += Whr[2*i+1] * hi;
            az += Whz[2*i] * lo; az += Whz[2*i+1] * hi;
            an += Whn[2*i] * lo; an += Whn[2*i+1] * hi;
        }
        v2f cr = {0.f,0.f}, cz = {0.f,0.f}, cn = {0.f,0.f};
        #pragma unroll
        for (int i = 0; i < 4; ++i) {
            float4 v = in4[i*4 + kq];
            v2f lo = {v.x, v.y}, hi = {v.z, v.w};
            cr += Wir[2*i] * lo; cr += Wir[2*i+1] * hi;
            cz += Wiz[2*i] * lo; cz += Wiz[2*i+1] * hi;
            cn += Win[2*i] * lo; cn += Win[2*i+1] * hi;
        }
        float rr  = fast_sigmoid(quad_red((ar.x + ar.y) + (cr.x + cr.y)) + br);
        float zz  = fast_sigmoid(quad_red((az.x + az.y) + (cz.x + cz.y)) + bz);
        float hnv = quad_red(an.x + an.y) + bh_n;
        float inv = quad_red(cn.x + cn.y) + bi_n;
        float nn  = fast_tanh(fmaf(rr, hnv, inv));
        float hnew = fmaf(zz, hode - nn, nn);              // (1-z)n + z*h_ode
        hj = hnew;

        if (kq == 0) sh_h[j] = hnew;
        __syncthreads();                                   // B5

        // ---- out_t = h_new @ W_out^T + b_out (feeds next step's prev_out) --
        v2f ao = {0.f, 0.f};
        #pragma unroll
        for (int i = 0; i < 4; ++i) {
            float4 v = h4[i*8 + ko];
            ao += Wo[2*i]   * (v2f){v.x, v.y};
            ao += Wo[2*i+1] * (v2f){v.z, v.w};
        }
        float o = quad_red(ao.x + ao.y);   // reduces within each quad
        o += __shfl_xor(o, 4);             // combine the octet's two quads
        o += bo;
        if (ko == 0) {
            sh_po[j64] = o;
            out[((size_t)b * TSTEP + s) * DIN + j64] = o;
        }
        __syncthreads();                                   // B6
    }
}

extern "C" void kernel_launch(void* const* d_in, const int* in_sizes, int n_in,
                              void* d_out, int out_size, void* d_ws, size_t ws_size,
                              hipStream_t stream) {
    (void)in_sizes; (void)n_in; (void)d_ws; (void)ws_size; (void)out_size;
    const float* x      = (const float*)d_in[0];
    const float* tp     = (const float*)d_in[1];
    const int*   mask   = (const int*)  d_in[2];
    const float* W_ih   = (const float*)d_in[3];
    const float* W_hh   = (const float*)d_in[4];
    const float* b_ih   = (const float*)d_in[5];
    const float* b_hh   = (const float*)d_in[6];
    const float* W_node = (const float*)d_in[7];
    const float* b_node = (const float*)d_in[8];
    const float* W_out  = (const float*)d_in[9];
    const float* b_out  = (const float*)d_in[10];
    float* outp = (float*)d_out;

    gruode_kernel<<<NB, TB, 0, stream>>>(x, tp, mask, W_ih, W_hh, b_ih, b_hh,
                                         W_node, b_node, W_out, b_out, outp);
}